// Round 1
// 3833.751 us; speedup vs baseline: 1.4220x; 1.4220x over previous
//
#include <hip/hip_runtime.h>
#include <math.h>

#define HID 64
#define HEADS 8
#define DH 8
#define TT 4
#define RR 6
#define LAYERS 2
#define NTOT 322000

static const int NS[TT]    = {100000, 200000, 20000, 2000};
static const int FEATS[TT] = {334, 512, 128, 128};
static const int RSRC[RR]  = {0, 1, 1, 2, 1, 3};
static const int RDST[RR]  = {1, 0, 2, 1, 3, 1};

// ---------------- utility ----------------

__global__ void fill_f(float* __restrict__ p, float v, int n) {
    int i = blockIdx.x * 256 + threadIdx.x;
    if (i < n) p[i] = v;
}

__global__ void fill_i(int* __restrict__ p, int v, int n) {
    int i = blockIdx.x * 256 + threadIdx.x;
    if (i < n) p[i] = v;
}

// ---------------- tiled fp32 GEMM: C[N x 64] = act(X[N x F] @ W[F x 64] + b) ----------------
// 256 threads; tile = 256 rows x 64 cols; each thread owns an 8x8 accumulator.
// PREG: apply exact GELU to X while staging. POST: 0=none, 1=relu, 2=skip-gate RMW on C.
// blockIdx.y selects (W,b,C) among the three provided (for fused K/Q/V).
template<int PREG, int POST>
__global__ __launch_bounds__(256) void gemm_n64(
    const float* __restrict__ X,
    const float* __restrict__ Wa, const float* __restrict__ Wb, const float* __restrict__ Wc,
    const float* __restrict__ ba, const float* __restrict__ bb, const float* __restrict__ bc,
    float* __restrict__ Ca, float* __restrict__ Cb, float* __restrict__ Cc,
    const float* __restrict__ skipv, int lt,
    int Nrows, int F)
{
    const float* W = Wa; const float* bias = ba; float* C = Ca;
    if (blockIdx.y == 1) { W = Wb; bias = bb; C = Cb; }
    else if (blockIdx.y == 2) { W = Wc; bias = bc; C = Cc; }

    __shared__ float xs[16][256];   // transposed X tile: xs[k][tile_row]
    __shared__ float ws[16][64];    // W tile: ws[k][col]

    int tid = threadIdx.x;
    int row0 = blockIdx.x * 256;
    int myrow = row0 + tid;                       // loader: one row per thread
    const float* xp = (myrow < Nrows) ? (X + (size_t)myrow * F) : (const float*)0;

    int cg = tid & 7;          // col group: cols cg*8 .. cg*8+7
    int rs = tid >> 3;         // row slot:  rows rs*8 .. rs*8+7 of the tile
    int xoff = rs * 8;
    int woff = cg * 8;

    int wi_f = tid >> 4;           // W loader: f index within tile (0..15)
    int wi_c = (tid & 15) * 4;     // W loader: col (x4)

    float acc[8][8];
#pragma unroll
    for (int i = 0; i < 8; ++i)
#pragma unroll
        for (int j = 0; j < 8; ++j) acc[i][j] = 0.f;

    const bool f4ok = ((F & 3) == 0);

    for (int k0 = 0; k0 < F; k0 += 16) {
        // --- fetch X row chunk into registers ---
        float xv[16];
        int rem = F - k0;
        if (xp) {
            if (rem >= 16) {
                if (f4ok) {
#pragma unroll
                    for (int j = 0; j < 4; ++j) {
                        float4 v = *(const float4*)(xp + k0 + 4 * j);
                        xv[4 * j + 0] = v.x; xv[4 * j + 1] = v.y;
                        xv[4 * j + 2] = v.z; xv[4 * j + 3] = v.w;
                    }
                } else {
#pragma unroll
                    for (int j = 0; j < 8; ++j) {
                        float2 v = *(const float2*)(xp + k0 + 2 * j);
                        xv[2 * j + 0] = v.x; xv[2 * j + 1] = v.y;
                    }
                }
            } else {
#pragma unroll
                for (int k = 0; k < 16; ++k) xv[k] = (k < rem) ? xp[k0 + k] : 0.f;
            }
        } else {
#pragma unroll
            for (int k = 0; k < 16; ++k) xv[k] = 0.f;
        }
        if (PREG) {
#pragma unroll
            for (int k = 0; k < 16; ++k) {
                float v = xv[k];
                xv[k] = 0.5f * v * (1.f + erff(v * 0.7071067811865475f));
            }
        }
        // --- fetch W tile chunk (one float4 per thread, fully coalesced) ---
        float4 wv;
        int f = k0 + wi_f;
        if (f < F) wv = *(const float4*)(W + (size_t)f * 64 + wi_c);
        else { wv.x = 0.f; wv.y = 0.f; wv.z = 0.f; wv.w = 0.f; }

        __syncthreads();   // previous tile fully consumed
#pragma unroll
        for (int k = 0; k < 16; ++k) xs[k][tid] = xv[k];
        *(float4*)&ws[wi_f][wi_c] = wv;
        __syncthreads();

        // --- compute: 16 k-steps x (8x8) FMAs ---
#pragma unroll
        for (int k = 0; k < 16; ++k) {
            float xr[8], wr[8];
#pragma unroll
            for (int j = 0; j < 8; ++j) xr[j] = xs[k][xoff + j];
#pragma unroll
            for (int j = 0; j < 8; ++j) wr[j] = ws[k][woff + j];
#pragma unroll
            for (int i = 0; i < 8; ++i)
#pragma unroll
                for (int j = 0; j < 8; ++j)
                    acc[i][j] = fmaf(xr[i], wr[j], acc[i][j]);
        }
    }

    // --- epilogue ---
    float bv[8];
#pragma unroll
    for (int j = 0; j < 8; ++j) bv[j] = bias[woff + j];
    float g = 1.f, invg = 0.f;
    if (POST == 2) {
        float s = skipv[lt];
        g = 1.f / (1.f + __expf(-s));
        invg = 1.f - g;
    }
#pragma unroll
    for (int i = 0; i < 8; ++i) {
        int r = row0 + xoff + i;
        if (r < Nrows) {
            size_t base = (size_t)r * 64 + woff;
            float o[8];
#pragma unroll
            for (int j = 0; j < 8; ++j) o[j] = acc[i][j] + bv[j];
            if (POST == 1) {
#pragma unroll
                for (int j = 0; j < 8; ++j) o[j] = fmaxf(o[j], 0.f);
            }
            if (POST == 2) {
#pragma unroll
                for (int j = 0; j < 8; ++j) o[j] = g * o[j] + invg * C[base + j];
            }
            float4 s0, s1;
            s0.x = o[0]; s0.y = o[1]; s0.z = o[2]; s0.w = o[3];
            s1.x = o[4]; s1.y = o[5]; s1.z = o[6]; s1.w = o[7];
            *(float4*)(C + base)     = s0;
            *(float4*)(C + base + 4) = s1;
        }
    }
}

// logits = h @ W_out + b_out
__global__ void out_proj(const float* __restrict__ h, const float* __restrict__ W,
                         const float* __restrict__ b, float* __restrict__ out, int n4) {
    int idx = blockIdx.x * 256 + threadIdx.x;
    if (idx >= n4) return;
    int row = idx >> 2, c = idx & 3;
    float acc = b[c];
    const float* hp = h + (size_t)row * 64;
    for (int f = 0; f < 64; ++f) acc = fmaf(hp[f], W[f * 4 + c], acc);
    out[idx] = acc;
}

// ---------------- CSR build ----------------

__global__ void hist_k(const int* __restrict__ dst, int* __restrict__ deg, int E) {
    int i = blockIdx.x * 256 + threadIdx.x;
    if (i < E) atomicAdd(&deg[dst[i]], 1);
}

// per-block sums over chunks of 1024
__global__ void scan1(const int* __restrict__ deg, int* __restrict__ bsum, int n) {
    __shared__ int sdata[256];
    int tid = threadIdx.x;
    int base = blockIdx.x * 1024 + tid * 4;
    int s = 0;
#pragma unroll
    for (int j = 0; j < 4; ++j) if (base + j < n) s += deg[base + j];
    sdata[tid] = s;
    __syncthreads();
    for (int off = 128; off > 0; off >>= 1) {
        if (tid < off) sdata[tid] += sdata[tid + off];
        __syncthreads();
    }
    if (tid == 0) bsum[blockIdx.x] = sdata[0];
}

// serial exclusive scan of block sums (nb <= ~200)
__global__ void scan2(int* __restrict__ bsum, int nb) {
    if (blockIdx.x == 0 && threadIdx.x == 0) {
        int run = 0;
        for (int i = 0; i < nb; ++i) { int t = bsum[i]; bsum[i] = run; run += t; }
    }
}

// write exclusive prefix into row_ptr
__global__ void scan3(const int* __restrict__ deg, const int* __restrict__ bsum,
                      int* __restrict__ rp, int n, int E) {
    __shared__ int sc[256];
    int tid = threadIdx.x;
    int base = blockIdx.x * 1024 + tid * 4;
    int v0 = 0, v1 = 0, v2 = 0, v3 = 0;
    if (base + 0 < n) v0 = deg[base + 0];
    if (base + 1 < n) v1 = deg[base + 1];
    if (base + 2 < n) v2 = deg[base + 2];
    if (base + 3 < n) v3 = deg[base + 3];
    int s = v0 + v1 + v2 + v3;
    sc[tid] = s;
    __syncthreads();
    for (int off = 1; off < 256; off <<= 1) {
        int t = (tid >= off) ? sc[tid - off] : 0;
        __syncthreads();
        sc[tid] += t;
        __syncthreads();
    }
    int run = bsum[blockIdx.x] + sc[tid] - s;   // exclusive prefix
    if (base + 0 < n) { rp[base + 0] = run; run += v0; }
    if (base + 1 < n) { rp[base + 1] = run; run += v1; }
    if (base + 2 < n) { rp[base + 2] = run; run += v2; }
    if (base + 3 < n) { rp[base + 3] = run; run += v3; }
    if (blockIdx.x == 0 && tid == 0) rp[n] = E;
}

__global__ void scatter_k(const int* __restrict__ src, const int* __restrict__ dst,
                          const int* __restrict__ rp, int* __restrict__ cnt,
                          int* __restrict__ col, int E) {
    int i = blockIdx.x * 256 + threadIdx.x;
    if (i >= E) return;
    int d = dst[i];
    int p = rp[d] + atomicAdd(&cnt[d], 1);
    col[p] = src[i];
}

// ---------------- fused per-relation attention ----------------
// One wave (64 lanes) per destination node; lane = head*8 + dim.
// score_e = k_e . qhat, qhat = (A_rel^T q) * P * scale (per node)
// accumulate sum(alpha*v) raw; apply M_rel once in epilogue.
__global__ __launch_bounds__(256) void rel_attn(
    const int* __restrict__ row_ptr, const int* __restrict__ col,
    const float* __restrict__ K, const float* __restrict__ Q, const float* __restrict__ V,
    const float* __restrict__ A, const float* __restrict__ M, const float* __restrict__ P,
    float* __restrict__ outb, int Nd)
{
    __shared__ float As[512], Ms[512], Ps[8];
    int tid = threadIdx.x;
    for (int i = tid; i < 512; i += 256) { As[i] = A[i]; Ms[i] = M[i]; }
    if (tid < 8) Ps[tid] = P[tid];
    __syncthreads();
    int wave = tid >> 6, lane = tid & 63;
    int d = blockIdx.x * 4 + wave;
    if (d >= Nd) return;
    int hh = lane >> 3, ff = lane & 7;
    int gbase = lane & 56;

    float q = Q[(size_t)d * 64 + lane];
    // qhat[hh,dd]  (this lane's dd == ff) = sum_f A[hh,dd,f] * q[hh,f]
    float qhat = 0.f;
#pragma unroll
    for (int f = 0; f < 8; ++f)
        qhat = fmaf(__shfl(q, gbase + f, 64), As[hh * 64 + ff * 8 + f], qhat);
    qhat *= Ps[hh] * 0.35355339059327373f;

    int e0 = row_ptr[d], e1 = row_ptr[d + 1];
    float m = -INFINITY, lsum = 0.f, acc = 0.f;
    for (int e = e0; e < e1; ++e) {
        int s = col[e];
        float kv = K[(size_t)s * 64 + lane];
        float vv = V[(size_t)s * 64 + lane];
        float p = kv * qhat;
        p += __shfl_xor(p, 1, 64);
        p += __shfl_xor(p, 2, 64);
        p += __shfl_xor(p, 4, 64);        // p = score for this head (all 8 lanes agree)
        float mn = fmaxf(m, p);
        float aa = __expf(m - mn);
        float w  = __expf(p - mn);
        lsum = lsum * aa + w;
        acc  = acc * aa + w * vv;
        m = mn;
    }
    // o[hh,ff] = sum_dd acc[hh,dd] * M[hh,dd,ff]
    float o = 0.f;
#pragma unroll
    for (int dd = 0; dd < 8; ++dd)
        o = fmaf(__shfl(acc, gbase + dd, 64), Ms[hh * 64 + dd * 8 + ff], o);
    float inv = (lsum > 0.f) ? 1.f / lsum : 0.f;
    outb[(size_t)d * 64 + lane] += o * inv;
}

// ---------------- launch ----------------

extern "C" void kernel_launch(void* const* d_in, const int* in_sizes, int n_in,
                              void* d_out, int out_size, void* d_ws, size_t ws_size,
                              hipStream_t stream) {
    const float* x[TT]    = {(const float*)d_in[0], (const float*)d_in[1],
                             (const float*)d_in[2], (const float*)d_in[3]};
    const float* Win[TT]  = {(const float*)d_in[4], (const float*)d_in[6],
                             (const float*)d_in[8], (const float*)d_in[10]};
    const float* bin[TT]  = {(const float*)d_in[5], (const float*)d_in[7],
                             (const float*)d_in[9], (const float*)d_in[11]};
    const float* KW = (const float*)d_in[12];
    const float* QW = (const float*)d_in[13];
    const float* VW = (const float*)d_in[14];
    const float* AW = (const float*)d_in[15];
    const float* Kb = (const float*)d_in[16];
    const float* Qb = (const float*)d_in[17];
    const float* Vb = (const float*)d_in[18];
    const float* Ab = (const float*)d_in[19];
    const float* skip  = (const float*)d_in[20];
    const float* A_rel = (const float*)d_in[21];
    const float* M_rel = (const float*)d_in[22];
    const float* P_rel = (const float*)d_in[23];
    const float* W_out = (const float*)d_in[24];
    const float* b_out = (const float*)d_in[25];
    const int* ei[RR] = {(const int*)d_in[26], (const int*)d_in[27], (const int*)d_in[28],
                         (const int*)d_in[29], (const int*)d_in[30], (const int*)d_in[31]};
    int E[RR];
    for (int r = 0; r < RR; ++r) E[r] = in_sizes[26 + r] / 2;

    float* ws = (float*)d_ws;
    size_t off = 0;
    float* h    = ws + off; off += (size_t)NTOT * 64;
    float* K    = ws + off; off += (size_t)NTOT * 64;
    float* Q    = ws + off; off += (size_t)NTOT * 64;
    float* V    = ws + off; off += (size_t)NTOT * 64;
    float* outb = ws + off; off += (size_t)NTOT * 64;
    int* ibase = (int*)(ws + off);
    size_t ioff = 0;
    int* col_all = ibase + ioff;               // 4M total
    int colOff[RR]; int acc_e = 0;
    for (int r = 0; r < RR; ++r) { colOff[r] = acc_e; acc_e += E[r]; }
    ioff += (size_t)acc_e;
    int* rp_all = ibase + ioff;
    int rpOff[RR]; int acc_rp = 0;
    for (int r = 0; r < RR; ++r) { rpOff[r] = acc_rp; acc_rp += NS[RDST[r]] + 1; }
    ioff += (size_t)acc_rp;
    int* deg  = ibase + ioff; ioff += 200000;
    int* cnt  = ibase + ioff; ioff += 200000;
    int* bsum = ibase + ioff; ioff += 256;

    int nodeOff[TT] = {0, 100000, 300000, 320000};

    // ---- CSR build (edge lists identical for both layers) ----
    for (int r = 0; r < RR; ++r) {
        int Nd = NS[RDST[r]];
        const int* srcIdx = ei[r];
        const int* dstIdx = ei[r] + E[r];
        int* rp  = rp_all + rpOff[r];
        int* col = col_all + colOff[r];
        fill_i<<<(Nd + 255) / 256, 256, 0, stream>>>(deg, 0, Nd);
        fill_i<<<(Nd + 255) / 256, 256, 0, stream>>>(cnt, 0, Nd);
        hist_k<<<(E[r] + 255) / 256, 256, 0, stream>>>(dstIdx, deg, E[r]);
        int nb = (Nd + 1023) / 1024;
        scan1<<<nb, 256, 0, stream>>>(deg, bsum, Nd);
        scan2<<<1, 64, 0, stream>>>(bsum, nb);
        scan3<<<nb, 256, 0, stream>>>(deg, bsum, rp, Nd, E[r]);
        scatter_k<<<(E[r] + 255) / 256, 256, 0, stream>>>(srcIdx, dstIdx, rp, cnt, col, E[r]);
    }

    // ---- input projections: h = relu(x @ W_in + b_in) ----
    for (int t = 0; t < TT; ++t) {
        dim3 grid((NS[t] + 255) / 256, 1);
        gemm_n64<0, 1><<<grid, 256, 0, stream>>>(
            x[t], Win[t], Win[t], Win[t], bin[t], bin[t], bin[t],
            h + (size_t)nodeOff[t] * 64, h + (size_t)nodeOff[t] * 64, h + (size_t)nodeOff[t] * 64,
            (const float*)0, 0, NS[t], FEATS[t]);
    }

    for (int l = 0; l < LAYERS; ++l) {
        // ---- fused K/Q/V projections (gridDim.y = 3) ----
        for (int t = 0; t < TT; ++t) {
            size_t wOff = (size_t)(l * TT + t) * 64 * 64;
            size_t bOff = (size_t)(l * TT + t) * 64;
            size_t nOff = (size_t)nodeOff[t] * 64;
            dim3 grid((NS[t] + 255) / 256, 3);
            gemm_n64<0, 0><<<grid, 256, 0, stream>>>(
                h + nOff, KW + wOff, QW + wOff, VW + wOff,
                Kb + bOff, Qb + bOff, Vb + bOff,
                K + nOff, Q + nOff, V + nOff,
                (const float*)0, 0, NS[t], 64);
        }
        fill_f<<<((size_t)NTOT * 64 + 255) / 256, 256, 0, stream>>>(outb, 0.f, NTOT * 64);

        for (int r = 0; r < RR; ++r) {
            int s = RSRC[r], d = RDST[r];
            int Nd = NS[d];
            const float* Ar = A_rel + (size_t)(l * RR + r) * HEADS * 64;
            const float* Mr = M_rel + (size_t)(l * RR + r) * HEADS * 64;
            const float* Pr = P_rel + (size_t)(l * RR + r) * HEADS;
            rel_attn<<<(Nd + 3) / 4, 256, 0, stream>>>(
                rp_all + rpOff[r], col_all + colOff[r],
                K + (size_t)nodeOff[s] * 64, Q + (size_t)nodeOff[d] * 64,
                V + (size_t)nodeOff[s] * 64, Ar, Mr, Pr,
                outb + (size_t)nodeOff[d] * 64, Nd);
        }

        // ---- h = g * (gelu(outb) @ AW + Ab) + (1-g) * h ----
        for (int t = 0; t < TT; ++t) {
            size_t wOff = (size_t)(l * TT + t) * 64 * 64;
            size_t bOff = (size_t)(l * TT + t) * 64;
            size_t nOff = (size_t)nodeOff[t] * 64;
            dim3 grid((NS[t] + 255) / 256, 1);
            gemm_n64<1, 2><<<grid, 256, 0, stream>>>(
                outb + nOff, AW + wOff, AW + wOff, AW + wOff,
                Ab + bOff, Ab + bOff, Ab + bOff,
                h + nOff, h + nOff, h + nOff,
                skip, l * TT + t, NS[t], 64);
        }
    }

    out_proj<<<(NS[0] * 4 + 255) / 256, 256, 0, stream>>>(h, W_out, b_out,
                                                          (float*)d_out, NS[0] * 4);
}

// Round 2
// 3784.199 us; speedup vs baseline: 1.4406x; 1.0131x over previous
//
#include <hip/hip_runtime.h>
#include <math.h>

#define HID 64
#define HEADS 8
#define DH 8
#define TT 4
#define RR 6
#define LAYERS 2
#define NTOT 322000

static const int NS[TT]    = {100000, 200000, 20000, 2000};
static const int FEATS[TT] = {334, 512, 128, 128};
static const int RSRC[RR]  = {0, 1, 1, 2, 1, 3};
static const int RDST[RR]  = {1, 0, 2, 1, 3, 1};

// ---------------- utility ----------------

__global__ void fill_f(float* __restrict__ p, float v, int n) {
    int i = blockIdx.x * 256 + threadIdx.x;
    if (i < n) p[i] = v;
}

__global__ void fill_i(int* __restrict__ p, int v, int n) {
    int i = blockIdx.x * 256 + threadIdx.x;
    if (i < n) p[i] = v;
}

// ---------------- tiled fp32 GEMM: C[N x 64] = act(X[N x F] + b) ----------------
// 256 threads; tile = 256 rows x 64 cols; each thread owns an 8x8 accumulator.
// Software-prefetch: next chunk's global loads issue BEFORE the compute phase,
// so HBM latency hides under the 16x64-FMA block (R2: VALUBusy was 38%,
// latency-exposed per-chunk load was the bottleneck).
// PREG: apply exact GELU to X at the LDS-store site. POST: 0=none, 1=relu,
// 2=skip-gate RMW on C. blockIdx.y selects (W,b,C) among three (fused K/Q/V).

__device__ __forceinline__ void load_x16(const float* __restrict__ xp, int F, int k0,
                                         bool f4ok, float xv[16]) {
    int rem = F - k0;
    if (xp && rem > 0) {
        if (rem >= 16) {
            if (f4ok) {
#pragma unroll
                for (int j = 0; j < 4; ++j) {
                    float4 v = *(const float4*)(xp + k0 + 4 * j);
                    xv[4 * j + 0] = v.x; xv[4 * j + 1] = v.y;
                    xv[4 * j + 2] = v.z; xv[4 * j + 3] = v.w;
                }
            } else {
#pragma unroll
                for (int j = 0; j < 8; ++j) {
                    float2 v = *(const float2*)(xp + k0 + 2 * j);
                    xv[2 * j + 0] = v.x; xv[2 * j + 1] = v.y;
                }
            }
        } else {
#pragma unroll
            for (int k = 0; k < 16; ++k) xv[k] = (k < rem) ? xp[k0 + k] : 0.f;
        }
    } else {
#pragma unroll
        for (int k = 0; k < 16; ++k) xv[k] = 0.f;
    }
}

__device__ __forceinline__ float4 load_w4(const float* __restrict__ W, int F,
                                          int f, int c) {
    float4 wv;
    if (f < F) wv = *(const float4*)(W + (size_t)f * 64 + c);
    else { wv.x = 0.f; wv.y = 0.f; wv.z = 0.f; wv.w = 0.f; }
    return wv;
}

template<int PREG, int POST>
__global__ __launch_bounds__(256) void gemm_n64(
    const float* __restrict__ X,
    const float* __restrict__ Wa, const float* __restrict__ Wb, const float* __restrict__ Wc,
    const float* __restrict__ ba, const float* __restrict__ bb, const float* __restrict__ bc,
    float* __restrict__ Ca, float* __restrict__ Cb, float* __restrict__ Cc,
    const float* __restrict__ skipv, int lt,
    int Nrows, int F)
{
    const float* W = Wa; const float* bias = ba; float* C = Ca;
    if (blockIdx.y == 1) { W = Wb; bias = bb; C = Cb; }
    else if (blockIdx.y == 2) { W = Wc; bias = bc; C = Cc; }

    __shared__ float xs[16][256];   // transposed X tile: xs[k][tile_row]
    __shared__ float ws[16][64];    // W tile: ws[k][col]

    int tid = threadIdx.x;
    int row0 = blockIdx.x * 256;
    int myrow = row0 + tid;                       // loader: one row per thread
    const float* xp = (myrow < Nrows) ? (X + (size_t)myrow * F) : (const float*)0;

    int cg = tid & 7;          // col group: cols cg*8 .. cg*8+7
    int rs = tid >> 3;         // row slot:  rows rs*8 .. rs*8+7 of the tile
    int xoff = rs * 8;
    int woff = cg * 8;

    int wi_f = tid >> 4;           // W loader: f index within tile (0..15)
    int wi_c = (tid & 15) * 4;     // W loader: col (x4)

    float acc[8][8];
#pragma unroll
    for (int i = 0; i < 8; ++i)
#pragma unroll
        for (int j = 0; j < 8; ++j) acc[i][j] = 0.f;

    const bool f4ok = ((F & 3) == 0);

    // prologue: prefetch chunk 0
    float xv[16];
    float4 wv;
    load_x16(xp, F, 0, f4ok, xv);
    wv = load_w4(W, F, wi_f, wi_c);

    for (int k0 = 0; k0 < F; k0 += 16) {
        __syncthreads();   // previous tile fully consumed
        // stage current chunk (waitcnt on the prefetched loads lands here)
        if (PREG) {
#pragma unroll
            for (int k = 0; k < 16; ++k) {
                float v = xv[k];
                xs[k][tid] = 0.5f * v * (1.f + erff(v * 0.7071067811865475f));
            }
        } else {
#pragma unroll
            for (int k = 0; k < 16; ++k) xs[k][tid] = xv[k];
        }
        *(float4*)&ws[wi_f][wi_c] = wv;
        __syncthreads();

        // issue NEXT chunk's global loads before compute: latency hides
        // under the 1024-FMA block below.
        if (k0 + 16 < F) {
            load_x16(xp, F, k0 + 16, f4ok, xv);
            wv = load_w4(W, F, k0 + 16 + wi_f, wi_c);
        }

        // --- compute: 16 k-steps x (8x8) FMAs ---
#pragma unroll
        for (int k = 0; k < 16; ++k) {
            float xr[8], wr[8];
#pragma unroll
            for (int j = 0; j < 8; ++j) xr[j] = xs[k][xoff + j];
#pragma unroll
            for (int j = 0; j < 8; ++j) wr[j] = ws[k][woff + j];
#pragma unroll
            for (int i = 0; i < 8; ++i)
#pragma unroll
                for (int j = 0; j < 8; ++j)
                    acc[i][j] = fmaf(xr[i], wr[j], acc[i][j]);
        }
    }

    // --- epilogue ---
    float bv[8];
#pragma unroll
    for (int j = 0; j < 8; ++j) bv[j] = bias[woff + j];
    float g = 1.f, invg = 0.f;
    if (POST == 2) {
        float s = skipv[lt];
        g = 1.f / (1.f + __expf(-s));
        invg = 1.f - g;
    }
#pragma unroll
    for (int i = 0; i < 8; ++i) {
        int r = row0 + xoff + i;
        if (r < Nrows) {
            size_t base = (size_t)r * 64 + woff;
            float o[8];
#pragma unroll
            for (int j = 0; j < 8; ++j) o[j] = acc[i][j] + bv[j];
            if (POST == 1) {
#pragma unroll
                for (int j = 0; j < 8; ++j) o[j] = fmaxf(o[j], 0.f);
            }
            if (POST == 2) {
#pragma unroll
                for (int j = 0; j < 8; ++j) o[j] = g * o[j] + invg * C[base + j];
            }
            float4 s0, s1;
            s0.x = o[0]; s0.y = o[1]; s0.z = o[2]; s0.w = o[3];
            s1.x = o[4]; s1.y = o[5]; s1.z = o[6]; s1.w = o[7];
            *(float4*)(C + base)     = s0;
            *(float4*)(C + base + 4) = s1;
        }
    }
}

// logits = h @ W_out + b_out
__global__ void out_proj(const float* __restrict__ h, const float* __restrict__ W,
                         const float* __restrict__ b, float* __restrict__ out, int n4) {
    int idx = blockIdx.x * 256 + threadIdx.x;
    if (idx >= n4) return;
    int row = idx >> 2, c = idx & 3;
    float acc = b[c];
    const float* hp = h + (size_t)row * 64;
    for (int f = 0; f < 64; ++f) acc = fmaf(hp[f], W[f * 4 + c], acc);
    out[idx] = acc;
}

// ---------------- CSR build ----------------

__global__ void hist_k(const int* __restrict__ dst, int* __restrict__ deg, int E) {
    int i = blockIdx.x * 256 + threadIdx.x;
    if (i < E) atomicAdd(&deg[dst[i]], 1);
}

// per-block sums over chunks of 1024
__global__ void scan1(const int* __restrict__ deg, int* __restrict__ bsum, int n) {
    __shared__ int sdata[256];
    int tid = threadIdx.x;
    int base = blockIdx.x * 1024 + tid * 4;
    int s = 0;
#pragma unroll
    for (int j = 0; j < 4; ++j) if (base + j < n) s += deg[base + j];
    sdata[tid] = s;
    __syncthreads();
    for (int off = 128; off > 0; off >>= 1) {
        if (tid < off) sdata[tid] += sdata[tid + off];
        __syncthreads();
    }
    if (tid == 0) bsum[blockIdx.x] = sdata[0];
}

// serial exclusive scan of block sums (nb <= ~200)
__global__ void scan2(int* __restrict__ bsum, int nb) {
    if (blockIdx.x == 0 && threadIdx.x == 0) {
        int run = 0;
        for (int i = 0; i < nb; ++i) { int t = bsum[i]; bsum[i] = run; run += t; }
    }
}

// write exclusive prefix into row_ptr
__global__ void scan3(const int* __restrict__ deg, const int* __restrict__ bsum,
                      int* __restrict__ rp, int n, int E) {
    __shared__ int sc[256];
    int tid = threadIdx.x;
    int base = blockIdx.x * 1024 + tid * 4;
    int v0 = 0, v1 = 0, v2 = 0, v3 = 0;
    if (base + 0 < n) v0 = deg[base + 0];
    if (base + 1 < n) v1 = deg[base + 1];
    if (base + 2 < n) v2 = deg[base + 2];
    if (base + 3 < n) v3 = deg[base + 3];
    int s = v0 + v1 + v2 + v3;
    sc[tid] = s;
    __syncthreads();
    for (int off = 1; off < 256; off <<= 1) {
        int t = (tid >= off) ? sc[tid - off] : 0;
        __syncthreads();
        sc[tid] += t;
        __syncthreads();
    }
    int run = bsum[blockIdx.x] + sc[tid] - s;   // exclusive prefix
    if (base + 0 < n) { rp[base + 0] = run; run += v0; }
    if (base + 1 < n) { rp[base + 1] = run; run += v1; }
    if (base + 2 < n) { rp[base + 2] = run; run += v2; }
    if (base + 3 < n) { rp[base + 3] = run; run += v3; }
    if (blockIdx.x == 0 && tid == 0) rp[n] = E;
}

__global__ void scatter_k(const int* __restrict__ src, const int* __restrict__ dst,
                          const int* __restrict__ rp, int* __restrict__ cnt,
                          int* __restrict__ col, int E) {
    int i = blockIdx.x * 256 + threadIdx.x;
    if (i >= E) return;
    int d = dst[i];
    int p = rp[d] + atomicAdd(&cnt[d], 1);
    col[p] = src[i];
}

// ---------------- fused per-relation attention ----------------
// One wave (64 lanes) per destination node; lane = head*8 + dim.
// score_e = k_e . qhat, qhat = (A_rel^T q) * P * scale (per node)
// accumulate sum(alpha*v) raw; apply M_rel once in epilogue.
__global__ __launch_bounds__(256) void rel_attn(
    const int* __restrict__ row_ptr, const int* __restrict__ col,
    const float* __restrict__ K, const float* __restrict__ Q, const float* __restrict__ V,
    const float* __restrict__ A, const float* __restrict__ M, const float* __restrict__ P,
    float* __restrict__ outb, int Nd)
{
    __shared__ float As[512], Ms[512], Ps[8];
    int tid = threadIdx.x;
    for (int i = tid; i < 512; i += 256) { As[i] = A[i]; Ms[i] = M[i]; }
    if (tid < 8) Ps[tid] = P[tid];
    __syncthreads();
    int wave = tid >> 6, lane = tid & 63;
    int d = blockIdx.x * 4 + wave;
    if (d >= Nd) return;
    int hh = lane >> 3, ff = lane & 7;
    int gbase = lane & 56;

    float q = Q[(size_t)d * 64 + lane];
    // qhat[hh,dd]  (this lane's dd == ff) = sum_f A[hh,dd,f] * q[hh,f]
    float qhat = 0.f;
#pragma unroll
    for (int f = 0; f < 8; ++f)
        qhat = fmaf(__shfl(q, gbase + f, 64), As[hh * 64 + ff * 8 + f], qhat);
    qhat *= Ps[hh] * 0.35355339059327373f;

    int e0 = row_ptr[d], e1 = row_ptr[d + 1];
    float m = -INFINITY, lsum = 0.f, acc = 0.f;
    for (int e = e0; e < e1; ++e) {
        int s = col[e];
        float kv = K[(size_t)s * 64 + lane];
        float vv = V[(size_t)s * 64 + lane];
        float p = kv * qhat;
        p += __shfl_xor(p, 1, 64);
        p += __shfl_xor(p, 2, 64);
        p += __shfl_xor(p, 4, 64);        // p = score for this head (all 8 lanes agree)
        float mn = fmaxf(m, p);
        float aa = __expf(m - mn);
        float w  = __expf(p - mn);
        lsum = lsum * aa + w;
        acc  = acc * aa + w * vv;
        m = mn;
    }
    // o[hh,ff] = sum_dd acc[hh,dd] * M[hh,dd,ff]
    float o = 0.f;
#pragma unroll
    for (int dd = 0; dd < 8; ++dd)
        o = fmaf(__shfl(acc, gbase + dd, 64), Ms[hh * 64 + dd * 8 + ff], o);
    float inv = (lsum > 0.f) ? 1.f / lsum : 0.f;
    outb[(size_t)d * 64 + lane] += o * inv;
}

// ---------------- launch ----------------

extern "C" void kernel_launch(void* const* d_in, const int* in_sizes, int n_in,
                              void* d_out, int out_size, void* d_ws, size_t ws_size,
                              hipStream_t stream) {
    const float* x[TT]    = {(const float*)d_in[0], (const float*)d_in[1],
                             (const float*)d_in[2], (const float*)d_in[3]};
    const float* Win[TT]  = {(const float*)d_in[4], (const float*)d_in[6],
                             (const float*)d_in[8], (const float*)d_in[10]};
    const float* bin[TT]  = {(const float*)d_in[5], (const float*)d_in[7],
                             (const float*)d_in[9], (const float*)d_in[11]};
    const float* KW = (const float*)d_in[12];
    const float* QW = (const float*)d_in[13];
    const float* VW = (const float*)d_in[14];
    const float* AW = (const float*)d_in[15];
    const float* Kb = (const float*)d_in[16];
    const float* Qb = (const float*)d_in[17];
    const float* Vb = (const float*)d_in[18];
    const float* Ab = (const float*)d_in[19];
    const float* skip  = (const float*)d_in[20];
    const float* A_rel = (const float*)d_in[21];
    const float* M_rel = (const float*)d_in[22];
    const float* P_rel = (const float*)d_in[23];
    const float* W_out = (const float*)d_in[24];
    const float* b_out = (const float*)d_in[25];
    const int* ei[RR] = {(const int*)d_in[26], (const int*)d_in[27], (const int*)d_in[28],
                         (const int*)d_in[29], (const int*)d_in[30], (const int*)d_in[31]};
    int E[RR];
    for (int r = 0; r < RR; ++r) E[r] = in_sizes[26 + r] / 2;

    float* ws = (float*)d_ws;
    size_t off = 0;
    float* h    = ws + off; off += (size_t)NTOT * 64;
    float* K    = ws + off; off += (size_t)NTOT * 64;
    float* Q    = ws + off; off += (size_t)NTOT * 64;
    float* V    = ws + off; off += (size_t)NTOT * 64;
    float* outb = ws + off; off += (size_t)NTOT * 64;
    int* ibase = (int*)(ws + off);
    size_t ioff = 0;
    int* col_all = ibase + ioff;               // 4M total
    int colOff[RR]; int acc_e = 0;
    for (int r = 0; r < RR; ++r) { colOff[r] = acc_e; acc_e += E[r]; }
    ioff += (size_t)acc_e;
    int* rp_all = ibase + ioff;
    int rpOff[RR]; int acc_rp = 0;
    for (int r = 0; r < RR; ++r) { rpOff[r] = acc_rp; acc_rp += NS[RDST[r]] + 1; }
    ioff += (size_t)acc_rp;
    int* deg  = ibase + ioff; ioff += 200000;
    int* cnt  = ibase + ioff; ioff += 200000;
    int* bsum = ibase + ioff; ioff += 256;

    int nodeOff[TT] = {0, 100000, 300000, 320000};

    // ---- CSR build (edge lists identical for both layers) ----
    for (int r = 0; r < RR; ++r) {
        int Nd = NS[RDST[r]];
        const int* srcIdx = ei[r];
        const int* dstIdx = ei[r] + E[r];
        int* rp  = rp_all + rpOff[r];
        int* col = col_all + colOff[r];
        fill_i<<<(Nd + 255) / 256, 256, 0, stream>>>(deg, 0, Nd);
        fill_i<<<(Nd + 255) / 256, 256, 0, stream>>>(cnt, 0, Nd);
        hist_k<<<(E[r] + 255) / 256, 256, 0, stream>>>(dstIdx, deg, E[r]);
        int nb = (Nd + 1023) / 1024;
        scan1<<<nb, 256, 0, stream>>>(deg, bsum, Nd);
        scan2<<<1, 64, 0, stream>>>(bsum, nb);
        scan3<<<nb, 256, 0, stream>>>(deg, bsum, rp, Nd, E[r]);
        scatter_k<<<(E[r] + 255) / 256, 256, 0, stream>>>(srcIdx, dstIdx, rp, cnt, col, E[r]);
    }

    // ---- input projections: h = relu(x @ W_in + b_in) ----
    for (int t = 0; t < TT; ++t) {
        dim3 grid((NS[t] + 255) / 256, 1);
        gemm_n64<0, 1><<<grid, 256, 0, stream>>>(
            x[t], Win[t], Win[t], Win[t], bin[t], bin[t], bin[t],
            h + (size_t)nodeOff[t] * 64, h + (size_t)nodeOff[t] * 64, h + (size_t)nodeOff[t] * 64,
            (const float*)0, 0, NS[t], FEATS[t]);
    }

    for (int l = 0; l < LAYERS; ++l) {
        // ---- fused K/Q/V projections (gridDim.y = 3) ----
        for (int t = 0; t < TT; ++t) {
            size_t wOff = (size_t)(l * TT + t) * 64 * 64;
            size_t bOff = (size_t)(l * TT + t) * 64;
            size_t nOff = (size_t)nodeOff[t] * 64;
            dim3 grid((NS[t] + 255) / 256, 3);
            gemm_n64<0, 0><<<grid, 256, 0, stream>>>(
                h + nOff, KW + wOff, QW + wOff, VW + wOff,
                Kb + bOff, Qb + bOff, Vb + bOff,
                K + nOff, Q + nOff, V + nOff,
                (const float*)0, 0, NS[t], 64);
        }
        fill_f<<<((size_t)NTOT * 64 + 255) / 256, 256, 0, stream>>>(outb, 0.f, NTOT * 64);

        for (int r = 0; r < RR; ++r) {
            int s = RSRC[r], d = RDST[r];
            int Nd = NS[d];
            const float* Ar = A_rel + (size_t)(l * RR + r) * HEADS * 64;
            const float* Mr = M_rel + (size_t)(l * RR + r) * HEADS * 64;
            const float* Pr = P_rel + (size_t)(l * RR + r) * HEADS;
            rel_attn<<<(Nd + 3) / 4, 256, 0, stream>>>(
                rp_all + rpOff[r], col_all + colOff[r],
                K + (size_t)nodeOff[s] * 64, Q + (size_t)nodeOff[d] * 64,
                V + (size_t)nodeOff[s] * 64, Ar, Mr, Pr,
                outb + (size_t)nodeOff[d] * 64, Nd);
        }

        // ---- h = g * (gelu(outb) @ AW + Ab) + (1-g) * h ----
        for (int t = 0; t < TT; ++t) {
            size_t wOff = (size_t)(l * TT + t) * 64 * 64;
            size_t bOff = (size_t)(l * TT + t) * 64;
            size_t nOff = (size_t)nodeOff[t] * 64;
            dim3 grid((NS[t] + 255) / 256, 1);
            gemm_n64<1, 2><<<grid, 256, 0, stream>>>(
                outb + nOff, AW + wOff, AW + wOff, AW + wOff,
                Ab + bOff, Ab + bOff, Ab + bOff,
                h + nOff, h + nOff, h + nOff,
                skip, l * TT + t, NS[t], 64);
        }
    }

    out_proj<<<(NS[0] * 4 + 255) / 256, 256, 0, stream>>>(h, W_out, b_out,
                                                          (float*)d_out, NS[0] * 4);
}

// Round 3
// 3176.189 us; speedup vs baseline: 1.7164x; 1.1914x over previous
//
#include <hip/hip_runtime.h>
#include <math.h>

#define HID 64
#define HEADS 8
#define DH 8
#define TT 4
#define RR 6
#define LAYERS 2
#define NTOT 322000

static const int NS[TT]    = {100000, 200000, 20000, 2000};
static const int FEATS[TT] = {334, 512, 128, 128};
static const int RSRC[RR]  = {0, 1, 1, 2, 1, 3};
static const int RDST[RR]  = {1, 0, 2, 1, 3, 1};

// ---------------- utility ----------------

__global__ void fill_f(float* __restrict__ p, float v, int n) {
    int i = blockIdx.x * 256 + threadIdx.x;
    if (i < n) p[i] = v;
}

__global__ void fill_i(int* __restrict__ p, int v, int n) {
    int i = blockIdx.x * 256 + threadIdx.x;
    if (i < n) p[i] = v;
}

// ---------------- tiled fp32 GEMM: C[N x 64] = act(X[N x F] + b) ----------------
// 256 threads; tile = 256 rows x 64 cols; each thread owns an 8x8 accumulator.
// Co-limited by LDS return BW (1 B/FLOP at 8x8 tile) and VALU — near its
// structural floor; left unchanged this round.

__device__ __forceinline__ void load_x16(const float* __restrict__ xp, int F, int k0,
                                         bool f4ok, float xv[16]) {
    int rem = F - k0;
    if (xp && rem > 0) {
        if (rem >= 16) {
            if (f4ok) {
#pragma unroll
                for (int j = 0; j < 4; ++j) {
                    float4 v = *(const float4*)(xp + k0 + 4 * j);
                    xv[4 * j + 0] = v.x; xv[4 * j + 1] = v.y;
                    xv[4 * j + 2] = v.z; xv[4 * j + 3] = v.w;
                }
            } else {
#pragma unroll
                for (int j = 0; j < 8; ++j) {
                    float2 v = *(const float2*)(xp + k0 + 2 * j);
                    xv[2 * j + 0] = v.x; xv[2 * j + 1] = v.y;
                }
            }
        } else {
#pragma unroll
            for (int k = 0; k < 16; ++k) xv[k] = (k < rem) ? xp[k0 + k] : 0.f;
        }
    } else {
#pragma unroll
        for (int k = 0; k < 16; ++k) xv[k] = 0.f;
    }
}

__device__ __forceinline__ float4 load_w4(const float* __restrict__ W, int F,
                                          int f, int c) {
    float4 wv;
    if (f < F) wv = *(const float4*)(W + (size_t)f * 64 + c);
    else { wv.x = 0.f; wv.y = 0.f; wv.z = 0.f; wv.w = 0.f; }
    return wv;
}

template<int PREG, int POST>
__global__ __launch_bounds__(256) void gemm_n64(
    const float* __restrict__ X,
    const float* __restrict__ Wa, const float* __restrict__ Wb, const float* __restrict__ Wc,
    const float* __restrict__ ba, const float* __restrict__ bb, const float* __restrict__ bc,
    float* __restrict__ Ca, float* __restrict__ Cb, float* __restrict__ Cc,
    const float* __restrict__ skipv, int lt,
    int Nrows, int F)
{
    const float* W = Wa; const float* bias = ba; float* C = Ca;
    if (blockIdx.y == 1) { W = Wb; bias = bb; C = Cb; }
    else if (blockIdx.y == 2) { W = Wc; bias = bc; C = Cc; }

    __shared__ float xs[16][256];   // transposed X tile: xs[k][tile_row]
    __shared__ float ws[16][64];    // W tile: ws[k][col]

    int tid = threadIdx.x;
    int row0 = blockIdx.x * 256;
    int myrow = row0 + tid;                       // loader: one row per thread
    const float* xp = (myrow < Nrows) ? (X + (size_t)myrow * F) : (const float*)0;

    int cg = tid & 7;          // col group: cols cg*8 .. cg*8+7
    int rs = tid >> 3;         // row slot:  rows rs*8 .. rs*8+7 of the tile
    int xoff = rs * 8;
    int woff = cg * 8;

    int wi_f = tid >> 4;           // W loader: f index within tile (0..15)
    int wi_c = (tid & 15) * 4;     // W loader: col (x4)

    float acc[8][8];
#pragma unroll
    for (int i = 0; i < 8; ++i)
#pragma unroll
        for (int j = 0; j < 8; ++j) acc[i][j] = 0.f;

    const bool f4ok = ((F & 3) == 0);

    // prologue: prefetch chunk 0
    float xv[16];
    float4 wv;
    load_x16(xp, F, 0, f4ok, xv);
    wv = load_w4(W, F, wi_f, wi_c);

    for (int k0 = 0; k0 < F; k0 += 16) {
        __syncthreads();   // previous tile fully consumed
        if (PREG) {
#pragma unroll
            for (int k = 0; k < 16; ++k) {
                float v = xv[k];
                xs[k][tid] = 0.5f * v * (1.f + erff(v * 0.7071067811865475f));
            }
        } else {
#pragma unroll
            for (int k = 0; k < 16; ++k) xs[k][tid] = xv[k];
        }
        *(float4*)&ws[wi_f][wi_c] = wv;
        __syncthreads();

        // issue NEXT chunk's global loads before compute
        if (k0 + 16 < F) {
            load_x16(xp, F, k0 + 16, f4ok, xv);
            wv = load_w4(W, F, k0 + 16 + wi_f, wi_c);
        }

        // --- compute: 16 k-steps x (8x8) FMAs ---
#pragma unroll
        for (int k = 0; k < 16; ++k) {
            float xr[8], wr[8];
#pragma unroll
            for (int j = 0; j < 8; ++j) xr[j] = xs[k][xoff + j];
#pragma unroll
            for (int j = 0; j < 8; ++j) wr[j] = ws[k][woff + j];
#pragma unroll
            for (int i = 0; i < 8; ++i)
#pragma unroll
                for (int j = 0; j < 8; ++j)
                    acc[i][j] = fmaf(xr[i], wr[j], acc[i][j]);
        }
    }

    // --- epilogue ---
    float bv[8];
#pragma unroll
    for (int j = 0; j < 8; ++j) bv[j] = bias[woff + j];
    float g = 1.f, invg = 0.f;
    if (POST == 2) {
        float s = skipv[lt];
        g = 1.f / (1.f + __expf(-s));
        invg = 1.f - g;
    }
#pragma unroll
    for (int i = 0; i < 8; ++i) {
        int r = row0 + xoff + i;
        if (r < Nrows) {
            size_t base = (size_t)r * 64 + woff;
            float o[8];
#pragma unroll
            for (int j = 0; j < 8; ++j) o[j] = acc[i][j] + bv[j];
            if (POST == 1) {
#pragma unroll
                for (int j = 0; j < 8; ++j) o[j] = fmaxf(o[j], 0.f);
            }
            if (POST == 2) {
#pragma unroll
                for (int j = 0; j < 8; ++j) o[j] = g * o[j] + invg * C[base + j];
            }
            float4 s0, s1;
            s0.x = o[0]; s0.y = o[1]; s0.z = o[2]; s0.w = o[3];
            s1.x = o[4]; s1.y = o[5]; s1.z = o[6]; s1.w = o[7];
            *(float4*)(C + base)     = s0;
            *(float4*)(C + base + 4) = s1;
        }
    }
}

// logits = h @ W_out + b_out
__global__ void out_proj(const float* __restrict__ h, const float* __restrict__ W,
                         const float* __restrict__ b, float* __restrict__ out, int n4) {
    int idx = blockIdx.x * 256 + threadIdx.x;
    if (idx >= n4) return;
    int row = idx >> 2, c = idx & 3;
    float acc = b[c];
    const float* hp = h + (size_t)row * 64;
    for (int f = 0; f < 64; ++f) acc = fmaf(hp[f], W[f * 4 + c], acc);
    out[idx] = acc;
}

// ---------------- CSR build ----------------

__global__ void hist_k(const int* __restrict__ dst, int* __restrict__ deg, int E) {
    int i = blockIdx.x * 256 + threadIdx.x;
    if (i < E) atomicAdd(&deg[dst[i]], 1);
}

// per-block sums over chunks of 1024
__global__ void scan1(const int* __restrict__ deg, int* __restrict__ bsum, int n) {
    __shared__ int sdata[256];
    int tid = threadIdx.x;
    int base = blockIdx.x * 1024 + tid * 4;
    int s = 0;
#pragma unroll
    for (int j = 0; j < 4; ++j) if (base + j < n) s += deg[base + j];
    sdata[tid] = s;
    __syncthreads();
    for (int off = 128; off > 0; off >>= 1) {
        if (tid < off) sdata[tid] += sdata[tid + off];
        __syncthreads();
    }
    if (tid == 0) bsum[blockIdx.x] = sdata[0];
}

// serial exclusive scan of block sums (nb <= ~200)
__global__ void scan2(int* __restrict__ bsum, int nb) {
    if (blockIdx.x == 0 && threadIdx.x == 0) {
        int run = 0;
        for (int i = 0; i < nb; ++i) { int t = bsum[i]; bsum[i] = run; run += t; }
    }
}

// write exclusive prefix into row_ptr
__global__ void scan3(const int* __restrict__ deg, const int* __restrict__ bsum,
                      int* __restrict__ rp, int n, int E) {
    __shared__ int sc[256];
    int tid = threadIdx.x;
    int base = blockIdx.x * 1024 + tid * 4;
    int v0 = 0, v1 = 0, v2 = 0, v3 = 0;
    if (base + 0 < n) v0 = deg[base + 0];
    if (base + 1 < n) v1 = deg[base + 1];
    if (base + 2 < n) v2 = deg[base + 2];
    if (base + 3 < n) v3 = deg[base + 3];
    int s = v0 + v1 + v2 + v3;
    sc[tid] = s;
    __syncthreads();
    for (int off = 1; off < 256; off <<= 1) {
        int t = (tid >= off) ? sc[tid - off] : 0;
        __syncthreads();
        sc[tid] += t;
        __syncthreads();
    }
    int run = bsum[blockIdx.x] + sc[tid] - s;   // exclusive prefix
    if (base + 0 < n) { rp[base + 0] = run; run += v0; }
    if (base + 1 < n) { rp[base + 1] = run; run += v1; }
    if (base + 2 < n) { rp[base + 2] = run; run += v2; }
    if (base + 3 < n) { rp[base + 3] = run; run += v3; }
    if (blockIdx.x == 0 && tid == 0) rp[n] = E;
}

__global__ void scatter_k(const int* __restrict__ src, const int* __restrict__ dst,
                          const int* __restrict__ rp, int* __restrict__ cnt,
                          int* __restrict__ col, int E) {
    int i = blockIdx.x * 256 + threadIdx.x;
    if (i >= E) return;
    int d = dst[i];
    int p = rp[d] + atomicAdd(&cnt[d], 1);
    col[p] = src[i];
}

// ---------------- fused attention, all relations in one launch ----------------
// One wave (64 lanes) per destination node; lane = head*8 + dim.
// 4-edge batching + 2-deep ping-pong prefetch: 8 gathers in flight per wave,
// one online-softmax rescale per 4 edges. Relations 0/3/5 share the paper
// destination buffer -> accumulate with atomicAdd.

struct RelTab {
    int blockStart[RR + 1];
    int rpOff[RR];
    int colOff[RR];
    int srcOff[RR];   // src node offset (rows)
    int dstOff[RR];   // dst node offset (rows)
    int nd[RR];
};

__global__ __launch_bounds__(256) void rel_attn_all(
    const int* __restrict__ rp_all, const int* __restrict__ col_all,
    const float* __restrict__ K, const float* __restrict__ Q, const float* __restrict__ V,
    const float* __restrict__ Abase, const float* __restrict__ Mbase,
    const float* __restrict__ Pbase,
    float* __restrict__ outb, RelTab tab)
{
    int bx = blockIdx.x;
    int r = 0;
#pragma unroll
    for (int i = 1; i < RR; ++i) if (bx >= tab.blockStart[i]) r = i;

    __shared__ float As[512], Ms[512], Ps[8];
    int tid = threadIdx.x;
    const float* A = Abase + (size_t)r * 512;
    const float* M = Mbase + (size_t)r * 512;
    const float* P = Pbase + (size_t)r * 8;
    for (int i = tid; i < 512; i += 256) { As[i] = A[i]; Ms[i] = M[i]; }
    if (tid < 8) Ps[tid] = P[tid];
    __syncthreads();

    int wave = tid >> 6, lane = tid & 63;
    int d = (bx - tab.blockStart[r]) * 4 + wave;
    if (d >= tab.nd[r]) return;

    const int* row_ptr = rp_all + tab.rpOff[r];
    const int* col     = col_all + tab.colOff[r];
    const float* Ks = K + (size_t)tab.srcOff[r] * 64;
    const float* Vs = V + (size_t)tab.srcOff[r] * 64;
    const float* Qd = Q + (size_t)tab.dstOff[r] * 64;
    float* outd = outb + (size_t)tab.dstOff[r] * 64;

    int hh = lane >> 3, ff = lane & 7, gbase = lane & 56;

    float q = Qd[(size_t)d * 64 + lane];
    float qhat = 0.f;
#pragma unroll
    for (int f = 0; f < 8; ++f)
        qhat = fmaf(__shfl(q, gbase + f, 64), As[hh * 64 + ff * 8 + f], qhat);
    qhat *= Ps[hh] * 0.35355339059327373f;

    int e0 = row_ptr[d], e1 = row_ptr[d + 1];
    float m = -INFINITY, lsum = 0.f, acc = 0.f;

    int e = e0;
    int eend4 = e0 + ((e1 - e0) & ~3);

    if (e < eend4) {
        float ka[4], va[4];
        {
            int sa[4];
#pragma unroll
            for (int j = 0; j < 4; ++j) sa[j] = col[e + j];
#pragma unroll
            for (int j = 0; j < 4; ++j) {
                ka[j] = Ks[(size_t)sa[j] * 64 + lane];
                va[j] = Vs[(size_t)sa[j] * 64 + lane];
            }
        }
        while (true) {
            int en = e + 4;
            bool more = (en < eend4);
            float kb[4], vb[4];
            if (more) {
                int sb[4];
#pragma unroll
                for (int j = 0; j < 4; ++j) sb[j] = col[en + j];
#pragma unroll
                for (int j = 0; j < 4; ++j) {
                    kb[j] = Ks[(size_t)sb[j] * 64 + lane];
                    vb[j] = Vs[(size_t)sb[j] * 64 + lane];
                }
            }
            // math on current group
            float p[4];
#pragma unroll
            for (int j = 0; j < 4; ++j) {
                float t = ka[j] * qhat;
                t += __shfl_xor(t, 1, 64);
                t += __shfl_xor(t, 2, 64);
                t += __shfl_xor(t, 4, 64);
                p[j] = t;
            }
            float mn = fmaxf(m, fmaxf(fmaxf(p[0], p[1]), fmaxf(p[2], p[3])));
            float aa = __expf(m - mn);
            float w0 = __expf(p[0] - mn), w1 = __expf(p[1] - mn);
            float w2 = __expf(p[2] - mn), w3 = __expf(p[3] - mn);
            lsum = lsum * aa + ((w0 + w1) + (w2 + w3));
            acc  = fmaf(acc, aa,
                   fmaf(w0, va[0], fmaf(w1, va[1], fmaf(w2, va[2], w3 * va[3]))));
            m = mn;
            e = en;
            if (!more) break;
#pragma unroll
            for (int j = 0; j < 4; ++j) { ka[j] = kb[j]; va[j] = vb[j]; }
        }
    }
    // remainder (<= 3 edges)
    for (; e < e1; ++e) {
        int s = col[e];
        float kv = Ks[(size_t)s * 64 + lane];
        float vv = Vs[(size_t)s * 64 + lane];
        float t = kv * qhat;
        t += __shfl_xor(t, 1, 64);
        t += __shfl_xor(t, 2, 64);
        t += __shfl_xor(t, 4, 64);
        float mn = fmaxf(m, t);
        float aa = __expf(m - mn);
        float w  = __expf(t - mn);
        lsum = lsum * aa + w;
        acc  = acc * aa + w * vv;
        m = mn;
    }

    float o = 0.f;
#pragma unroll
    for (int dd = 0; dd < 8; ++dd)
        o = fmaf(__shfl(acc, gbase + dd, 64), Ms[hh * 64 + dd * 8 + ff], o);
    float inv = (lsum > 0.f) ? 1.f / lsum : 0.f;
    atomicAdd(&outd[(size_t)d * 64 + lane], o * inv);
}

// ---------------- launch ----------------

extern "C" void kernel_launch(void* const* d_in, const int* in_sizes, int n_in,
                              void* d_out, int out_size, void* d_ws, size_t ws_size,
                              hipStream_t stream) {
    const float* x[TT]    = {(const float*)d_in[0], (const float*)d_in[1],
                             (const float*)d_in[2], (const float*)d_in[3]};
    const float* Win[TT]  = {(const float*)d_in[4], (const float*)d_in[6],
                             (const float*)d_in[8], (const float*)d_in[10]};
    const float* bin[TT]  = {(const float*)d_in[5], (const float*)d_in[7],
                             (const float*)d_in[9], (const float*)d_in[11]};
    const float* KW = (const float*)d_in[12];
    const float* QW = (const float*)d_in[13];
    const float* VW = (const float*)d_in[14];
    const float* AW = (const float*)d_in[15];
    const float* Kb = (const float*)d_in[16];
    const float* Qb = (const float*)d_in[17];
    const float* Vb = (const float*)d_in[18];
    const float* Ab = (const float*)d_in[19];
    const float* skip  = (const float*)d_in[20];
    const float* A_rel = (const float*)d_in[21];
    const float* M_rel = (const float*)d_in[22];
    const float* P_rel = (const float*)d_in[23];
    const float* W_out = (const float*)d_in[24];
    const float* b_out = (const float*)d_in[25];
    const int* ei[RR] = {(const int*)d_in[26], (const int*)d_in[27], (const int*)d_in[28],
                         (const int*)d_in[29], (const int*)d_in[30], (const int*)d_in[31]};
    int E[RR];
    for (int r = 0; r < RR; ++r) E[r] = in_sizes[26 + r] / 2;

    float* ws = (float*)d_ws;
    size_t off = 0;
    float* h    = ws + off; off += (size_t)NTOT * 64;
    float* K    = ws + off; off += (size_t)NTOT * 64;
    float* Q    = ws + off; off += (size_t)NTOT * 64;
    float* V    = ws + off; off += (size_t)NTOT * 64;
    float* outb = ws + off; off += (size_t)NTOT * 64;
    int* ibase = (int*)(ws + off);
    size_t ioff = 0;
    int* col_all = ibase + ioff;               // 4M total
    int colOff[RR]; int acc_e = 0;
    for (int r = 0; r < RR; ++r) { colOff[r] = acc_e; acc_e += E[r]; }
    ioff += (size_t)acc_e;
    int* rp_all = ibase + ioff;
    int rpOff[RR]; int acc_rp = 0;
    for (int r = 0; r < RR; ++r) { rpOff[r] = acc_rp; acc_rp += NS[RDST[r]] + 1; }
    ioff += (size_t)acc_rp;
    int* deg  = ibase + ioff; ioff += 200000;
    int* cnt  = ibase + ioff; ioff += 200000;
    int* bsum = ibase + ioff; ioff += 256;

    int nodeOff[TT] = {0, 100000, 300000, 320000};

    // ---- CSR build (edge lists identical for both layers) ----
    for (int r = 0; r < RR; ++r) {
        int Nd = NS[RDST[r]];
        const int* srcIdx = ei[r];
        const int* dstIdx = ei[r] + E[r];
        int* rp  = rp_all + rpOff[r];
        int* col = col_all + colOff[r];
        fill_i<<<(Nd + 255) / 256, 256, 0, stream>>>(deg, 0, Nd);
        fill_i<<<(Nd + 255) / 256, 256, 0, stream>>>(cnt, 0, Nd);
        hist_k<<<(E[r] + 255) / 256, 256, 0, stream>>>(dstIdx, deg, E[r]);
        int nb = (Nd + 1023) / 1024;
        scan1<<<nb, 256, 0, stream>>>(deg, bsum, Nd);
        scan2<<<1, 64, 0, stream>>>(bsum, nb);
        scan3<<<nb, 256, 0, stream>>>(deg, bsum, rp, Nd, E[r]);
        scatter_k<<<(E[r] + 255) / 256, 256, 0, stream>>>(srcIdx, dstIdx, rp, cnt, col, E[r]);
    }

    // ---- relation table for the merged attention kernel ----
    RelTab tab;
    int bacc = 0;
    for (int r = 0; r < RR; ++r) {
        tab.blockStart[r] = bacc;
        bacc += (NS[RDST[r]] + 3) / 4;
        tab.rpOff[r]  = rpOff[r];
        tab.colOff[r] = colOff[r];
        tab.srcOff[r] = nodeOff[RSRC[r]];
        tab.dstOff[r] = nodeOff[RDST[r]];
        tab.nd[r]     = NS[RDST[r]];
    }
    tab.blockStart[RR] = bacc;

    // ---- input projections: h = relu(x @ W_in + b_in) ----
    for (int t = 0; t < TT; ++t) {
        dim3 grid((NS[t] + 255) / 256, 1);
        gemm_n64<0, 1><<<grid, 256, 0, stream>>>(
            x[t], Win[t], Win[t], Win[t], bin[t], bin[t], bin[t],
            h + (size_t)nodeOff[t] * 64, h + (size_t)nodeOff[t] * 64, h + (size_t)nodeOff[t] * 64,
            (const float*)0, 0, NS[t], FEATS[t]);
    }

    for (int l = 0; l < LAYERS; ++l) {
        // ---- fused K/Q/V projections (gridDim.y = 3) ----
        for (int t = 0; t < TT; ++t) {
            size_t wOff = (size_t)(l * TT + t) * 64 * 64;
            size_t bOff = (size_t)(l * TT + t) * 64;
            size_t nOff = (size_t)nodeOff[t] * 64;
            dim3 grid((NS[t] + 255) / 256, 3);
            gemm_n64<0, 0><<<grid, 256, 0, stream>>>(
                h + nOff, KW + wOff, QW + wOff, VW + wOff,
                Kb + bOff, Qb + bOff, Vb + bOff,
                K + nOff, Q + nOff, V + nOff,
                (const float*)0, 0, NS[t], 64);
        }
        fill_f<<<((size_t)NTOT * 64 + 255) / 256, 256, 0, stream>>>(outb, 0.f, NTOT * 64);

        rel_attn_all<<<bacc, 256, 0, stream>>>(
            rp_all, col_all, K, Q, V,
            A_rel + (size_t)l * RR * 512,
            M_rel + (size_t)l * RR * 512,
            P_rel + (size_t)l * RR * 8,
            outb, tab);

        // ---- h = g * (gelu(outb) @ AW + Ab) + (1-g) * h ----
        for (int t = 0; t < TT; ++t) {
            size_t wOff = (size_t)(l * TT + t) * 64 * 64;
            size_t bOff = (size_t)(l * TT + t) * 64;
            size_t nOff = (size_t)nodeOff[t] * 64;
            dim3 grid((NS[t] + 255) / 256, 1);
            gemm_n64<1, 2><<<grid, 256, 0, stream>>>(
                outb + nOff, AW + wOff, AW + wOff, AW + wOff,
                Ab + bOff, Ab + bOff, Ab + bOff,
                h + nOff, h + nOff, h + nOff,
                skip, l * TT + t, NS[t], 64);
        }
    }

    out_proj<<<(NS[0] * 4 + 255) / 256, 256, 0, stream>>>(h, W_out, b_out,
                                                          (float*)d_out, NS[0] * 4);
}